// Round 14
// baseline (978.474 us; speedup 1.0000x reference)
//
#include <hip/hip_runtime.h>
#include <hip/hip_bf16.h>
#include <hip/hip_fp8.h>
#include <stdint.h>

#define BETA 0.5f
#define IGNORE_INDEX (-100)
// Weights pre-scaled x64 into fp8 (avoids e4m3 subnormals for sigma~1/64);
// descale is folded into the MX block-scale of B: 2^-6 (E8M0 0x79), exact.
#define WSCALE 64.0f
#define SCALE_ONE  0x7F7F7F7Fu  // E8M0 1.0 per byte
#define SCALE_D64  0x79797979u  // E8M0 2^-6 per byte

typedef float f32x4 __attribute__((ext_vector_type(4)));
typedef int   i32x4 __attribute__((ext_vector_type(4)));
typedef int   i32x8 __attribute__((ext_vector_type(8)));

// ---------------------------------------------------------------- converts
__global__ __launch_bounds__(256) void f32_to_fp8_kernel(
    const float* __restrict__ in, uint8_t* __restrict__ out, int n, float scale) {
  int i = (blockIdx.x * blockDim.x + threadIdx.x) * 8;
  const int stride = gridDim.x * blockDim.x * 8;
  for (; i < n; i += stride) {
    float4 v0 = *reinterpret_cast<const float4*>(in + i);
    float4 v1 = *reinterpret_cast<const float4*>(in + i + 4);
    const float f[8] = {v0.x, v0.y, v0.z, v0.w, v1.x, v1.y, v1.z, v1.w};
    union { uint8_t b[8]; uint2 u; } o;
#pragma unroll
    for (int j = 0; j < 8; ++j) {
      __hip_fp8_e4m3 h(f[j] * scale);
      o.b[j] = h.__x;
    }
    *reinterpret_cast<uint2*>(out + i) = o.u;
  }
}

// ---------------------------------------------------------------- GEMM (NT)
// C[n][v] = sum_k A[n][k] * (W[v][k]*64) * 2^-6, A/B fp8 e4m3, C bf16.
// MX-scaled MFMA f32_16x16x128_f8f6f4 (2x the non-scaled fp8 rate, m21/m148):
// uniform E8M0 scales (A=1.0, B=2^-6) make the per-block scale mapping
// irrelevant and fold the W descale in exactly.  K-ordering inside the
// 8-VGPR operands is layout-risk-free: any shared k-permutation of A and B
// computes the same dot product (r12 argument).
// 256x256 tile, BK=128, 8 waves (2Mx4N), r13 schedule: barrier-free tile
// body (2 chunks), 1 boundary barrier, counted vmcnt(4), setprio, XCD
// swizzle.  LDS: 2 buf x (A 32K | B 32K) = 128 KiB.  Row = 128 B = one
// bank window; phys_quad = q ^ (row&7) -> 8-lane groups hit 8 distinct
// 16-B units (0 conflicts, r13-validated model).
// Merged launch: blocks [0,half) = teacher, [half,2*half) = student.

__global__ __launch_bounds__(512, 2) void gemm_mx_kernel(
    const uint8_t* __restrict__ At, const uint8_t* __restrict__ Bt,
    uint16_t* __restrict__ Ct, int Kt,
    const uint8_t* __restrict__ As_, const uint8_t* __restrict__ Bs_,
    uint16_t* __restrict__ Cs, int Ks,
    int V, int RT, int CT) {
  __shared__ __align__(16) uint8_t lds[131072];

  const int half = RT * CT;
  const uint8_t *A, *B;
  uint16_t* C;
  int K, bidx = blockIdx.x;
  if (bidx < half) { A = At; B = Bt; C = Ct; K = Kt; }
  else             { A = As_; B = Bs_; C = Cs; K = Ks; bidx -= half; }

  int L = ((half & 7) == 0) ? ((bidx & 7) * (half >> 3) + (bidx >> 3)) : bidx;
  const int rt = L % RT;
  const int ct = L / RT;
  const int row0 = rt * 256;
  const int col0 = ct * 256;

  const int i  = threadIdx.x;      // 0..511
  const int w  = i >> 6;
  const int l  = i & 63;
  const int wl = l & 15;
  const int kg = l >> 4;           // k-quarter 0..3 (32 k each)
  const int wr = w >> 2;           // wave row 0..1 (128 out rows)
  const int wc = w & 3;            // wave col 0..3 (64 out cols)

  const int nT = K >> 7;           // BK = 128

  // ---- staging: thread i -> (rowgroup rg = i>>3, phys quad p = i&7).
  // 4 passes j: row = j*64 + rg; XOR term (row&7) == (rg&7) for all j.
  const int rg = i >> 3;           // 0..63
  const int p8 = i & 7;
  const int qsrc = p8 ^ (rg & 7);
  const uint8_t* aSrc = A + (size_t)(row0 + rg) * K + qsrc * 16;
  const uint8_t* bSrc = B + (size_t)(col0 + rg) * K + qsrc * 16;
  uint8_t* ldsu = lds;

#define GL(srcp, dstp)                                                     \
  __builtin_amdgcn_global_load_lds(                                        \
      (const __attribute__((address_space(1))) void*)(srcp),               \
      (__attribute__((address_space(3))) void*)(dstp), 16, 0, 0)

#define STAGE_A(TT)                                                        \
  do {                                                                     \
    const uint8_t* _s = aSrc + (size_t)(TT) * 128;                         \
    uint8_t* _d = ldsu + (((TT) & 1) * 65536) + i * 16;                    \
    GL(_s, _d);                                                            \
    GL(_s + (size_t)64 * K,  _d + 8192);                                   \
    GL(_s + (size_t)128 * K, _d + 16384);                                  \
    GL(_s + (size_t)192 * K, _d + 24576);                                  \
  } while (0)

#define STAGE_B(TT)                                                        \
  do {                                                                     \
    const uint8_t* _s = bSrc + (size_t)(TT) * 128;                         \
    uint8_t* _d = ldsu + (((TT) & 1) * 65536) + 32768 + i * 16;            \
    GL(_s, _d);                                                            \
    GL(_s + (size_t)64 * K,  _d + 8192);                                   \
    GL(_s + (size_t)128 * K, _d + 16384);                                  \
    GL(_s + (size_t)192 * K, _d + 24576);                                  \
  } while (0)

  // ---- ds_read_b128 offsets: row r, k-quads 2kg, 2kg+1; phys = q^(wl&7)
  // (row bases are multiples of 16 so (r&7) == (wl&7)).
  int offA[8][2], offB[4][2];
#pragma unroll
  for (int m = 0; m < 8; ++m) {
    const int r = wr * 128 + m * 16 + wl;
#pragma unroll
    for (int s = 0; s < 2; ++s)
      offA[m][s] = r * 128 + (((2 * kg + s) ^ (wl & 7)) * 16);
  }
#pragma unroll
  for (int n = 0; n < 4; ++n) {
    const int r = wc * 64 + n * 16 + wl;
#pragma unroll
    for (int s = 0; s < 2; ++s)
      offB[n][s] = 32768 + r * 128 + (((2 * kg + s) ^ (wl & 7)) * 16);
  }

  f32x4 acc[8][4] = {};
  i32x8 aF[4], bF[4];

#define LOADFRAG(dst, base, o0, o1)                                        \
  do {                                                                     \
    i32x4 _lo = *reinterpret_cast<const i32x4*>((base) + (o0));            \
    i32x4 _hi = *reinterpret_cast<const i32x4*>((base) + (o1));            \
    dst[0] = _lo[0]; dst[1] = _lo[1]; dst[2] = _lo[2]; dst[3] = _lo[3];    \
    dst[4] = _hi[0]; dst[5] = _hi[1]; dst[6] = _hi[2]; dst[7] = _hi[3];    \
  } while (0)

  // ---- prologue: stage A(0)+B(0)+B(1); drain tile0 (vmcnt 4)
  STAGE_A(0); STAGE_B(0);
  if (nT > 1) {
    STAGE_B(1);
    asm volatile("s_waitcnt vmcnt(4)" ::: "memory");
  } else {
    asm volatile("s_waitcnt vmcnt(0)" ::: "memory");
  }
  __builtin_amdgcn_s_barrier();
  __builtin_amdgcn_sched_barrier(0);

  for (int T = 0; T < nT; ++T) {
    const uint8_t* bb = lds + (T & 1) * 65536;
    const bool stg1 = (T + 1) < nT;
    const bool stg2 = (T + 2) < nT;

    // chunk 1: read A m0..3 + B n0..3 (16 b128); stage A(T+1); MFMA m0..3
#pragma unroll
    for (int m = 0; m < 4; ++m)
      LOADFRAG(aF[m], bb, offA[m][0], offA[m][1]);
#pragma unroll
    for (int n = 0; n < 4; ++n)
      LOADFRAG(bF[n], bb, offB[n][0], offB[n][1]);
    if (stg1) STAGE_A(T + 1);
    __builtin_amdgcn_s_setprio(1);
#pragma unroll
    for (int m = 0; m < 4; ++m)
#pragma unroll
      for (int n = 0; n < 4; ++n)
        acc[m][n] = __builtin_amdgcn_mfma_scale_f32_16x16x128_f8f6f4(
            aF[m], bF[n], acc[m][n], 0, 0, 0, SCALE_ONE, 0, SCALE_D64);
    __builtin_amdgcn_s_setprio(0);

    // chunk 2: read A m4..7 (8 b128); stage B(T+2); MFMA m4..7
#pragma unroll
    for (int m = 0; m < 4; ++m)
      LOADFRAG(aF[m], bb, offA[4 + m][0], offA[4 + m][1]);
    if (stg2) STAGE_B(T + 2);
    __builtin_amdgcn_s_setprio(1);
#pragma unroll
    for (int m = 0; m < 4; ++m)
#pragma unroll
      for (int n = 0; n < 4; ++n)
        acc[4 + m][n] = __builtin_amdgcn_mfma_scale_f32_16x16x128_f8f6f4(
            aF[m], bF[n], acc[4 + m][n], 0, 0, 0, SCALE_ONE, 0, SCALE_D64);
    __builtin_amdgcn_s_setprio(0);

    // boundary: counted vmcnt (drains A(T+1)+older, leaves B(T+2)), barrier
    if (stg2) {
      asm volatile("s_waitcnt vmcnt(4)" ::: "memory");
    } else {
      asm volatile("s_waitcnt vmcnt(0)" ::: "memory");
    }
    __builtin_amdgcn_s_barrier();
    __builtin_amdgcn_sched_barrier(0);
  }

  // epilogue: C/D layout col=lane&15, row=(lane>>4)*4+reg (shape-determined)
#pragma unroll
  for (int mg = 0; mg < 8; ++mg)
#pragma unroll
    for (int ng = 0; ng < 4; ++ng)
#pragma unroll
      for (int r = 0; r < 4; ++r) {
        const int row = row0 + wr * 128 + mg * 16 + kg * 4 + r;
        const int col = col0 + wc * 64 + ng * 16 + wl;
        __hip_bfloat16 bv = __float2bfloat16(acc[mg][ng][r]);
        C[(size_t)row * V + col] = *reinterpret_cast<const uint16_t*>(&bv);
      }
#undef LOADFRAG
#undef STAGE_A
#undef STAGE_B
#undef GL
}

// ---------------------------------------------------------------- JSD rows
__device__ __forceinline__ void unpack8(uint4 v, float* f) {
  uint32_t w[4] = {v.x, v.y, v.z, v.w};
#pragma unroll
  for (int j = 0; j < 4; ++j) {
    union { uint32_t u; float x; } lo, hi;
    lo.u = (w[j] & 0xffffu) << 16;
    hi.u = w[j] & 0xffff0000u;
    f[2 * j] = lo.x;
    f[2 * j + 1] = hi.x;
  }
}

__device__ __forceinline__ float blockReduce(float v, float* sh) {
#pragma unroll
  for (int o = 32; o >= 1; o >>= 1) v += __shfl_xor(v, o, 64);
  const int w = threadIdx.x >> 6;
  __syncthreads();
  if ((threadIdx.x & 63) == 0) sh[w] = v;
  __syncthreads();
  float r = sh[0];
#pragma unroll
  for (int i = 1; i < 4; ++i) r += sh[i];
  return r;
}

// online-LSE load pass (1 global sweep, fused max+sum) + 1 LDS JSD pass.
__global__ __launch_bounds__(256) void jsd_rows_kernel(
    const uint16_t* __restrict__ SL, const uint16_t* __restrict__ TL,
    float* __restrict__ per_tok, int V) {
  __shared__ __align__(16) uint16_t rowS[32000];
  __shared__ __align__(16) uint16_t rowT[32000];
  __shared__ float redM[2][4], redS[2][4], red[4];

  const int t = threadIdx.x;
  const int row = blockIdx.x;
  const uint4* gS = reinterpret_cast<const uint4*>(SL + (size_t)row * V);
  const uint4* gT = reinterpret_cast<const uint4*>(TL + (size_t)row * V);
  uint4* lS = reinterpret_cast<uint4*>(rowS);
  uint4* lT = reinterpret_cast<uint4*>(rowT);
  const int nvec = V >> 3;  // 4000

  float mS = -3.0e38f, sS = 0.f, mT = -3.0e38f, sT = 0.f;
  for (int i = t; i < nvec; i += 256) {
    uint4 vs = gS[i], vt = gT[i];
    lS[i] = vs; lT[i] = vt;
    float fs[8], ft[8];
    unpack8(vs, fs);
    unpack8(vt, ft);
    float vmS = fs[0], vmT = ft[0];
#pragma unroll
    for (int j = 1; j < 8; ++j) { vmS = fmaxf(vmS, fs[j]); vmT = fmaxf(vmT, ft[j]); }
    if (vmS > mS) { sS *= __expf(mS - vmS); mS = vmS; }
    if (vmT > mT) { sT *= __expf(mT - vmT); mT = vmT; }
#pragma unroll
    for (int j = 0; j < 8; ++j) { sS += __expf(fs[j] - mS); sT += __expf(ft[j] - mT); }
  }

#pragma unroll
  for (int o = 32; o >= 1; o >>= 1) {
    float mo = __shfl_xor(mS, o, 64), so = __shfl_xor(sS, o, 64);
    float mn = fmaxf(mS, mo);
    sS = sS * __expf(mS - mn) + so * __expf(mo - mn); mS = mn;
    mo = __shfl_xor(mT, o, 64); so = __shfl_xor(sT, o, 64);
    mn = fmaxf(mT, mo);
    sT = sT * __expf(mT - mn) + so * __expf(mo - mn); mT = mn;
  }
  const int wv = t >> 6;
  if ((t & 63) == 0) {
    redM[0][wv] = mS; redS[0][wv] = sS;
    redM[1][wv] = mT; redS[1][wv] = sT;
  }
  __syncthreads();   // covers (m,s) publication AND the LDS row writes
  float M0 = redM[0][0], S0 = redS[0][0];
  float M1 = redM[1][0], S1 = redS[1][0];
#pragma unroll
  for (int k = 1; k < 4; ++k) {
    float m2 = redM[0][k], s2 = redS[0][k];
    float mn = fmaxf(M0, m2);
    S0 = S0 * __expf(M0 - mn) + s2 * __expf(m2 - mn); M0 = mn;
    m2 = redM[1][k]; s2 = redS[1][k];
    mn = fmaxf(M1, m2);
    S1 = S1 * __expf(M1 - mn) + s2 * __expf(m2 - mn); M1 = mn;
  }
  const float lseS = M0 + __logf(S0);
  const float lseT = M1 + __logf(S1);

  float acc = 0.f;
  for (int i = t; i < nvec; i += 256) {
    float fs[8], ft[8];
    unpack8(lS[i], fs);
    unpack8(lT[i], ft);
#pragma unroll
    for (int j = 0; j < 8; ++j) {
      const float lq = fs[j] - lseS;
      const float lp = ft[j] - lseT;
      const float q = __expf(lq);
      const float p = __expf(lp);
      const float m = BETA * p + (1.f - BETA) * q;
      const float lm = __logf(m);
      acc += BETA * p * (lp - lm) + (1.f - BETA) * q * (lq - lm);
    }
  }
  acc = blockReduce(acc, red);
  if (t == 0) per_tok[row] = acc;
}

// ---------------------------------------------------------------- finalize
__global__ __launch_bounds__(256) void finalize_kernel(
    const float* __restrict__ per_tok, const int* __restrict__ tgt,
    float* __restrict__ out, int N) {
  __shared__ float redf[4];
  __shared__ int redi[4];
  float s = 0.f;
  int c = 0;
  for (int i = threadIdx.x; i < N; i += 256) {
    if (tgt[i] != IGNORE_INDEX) { s += per_tok[i]; c += 1; }
  }
#pragma unroll
  for (int o = 32; o >= 1; o >>= 1) {
    s += __shfl_xor(s, o, 64);
    c += __shfl_xor(c, o, 64);
  }
  const int w = threadIdx.x >> 6;
  if ((threadIdx.x & 63) == 0) { redf[w] = s; redi[w] = c; }
  __syncthreads();
  if (threadIdx.x == 0) {
    float st = 0.f;
    int ct = 0;
#pragma unroll
    for (int i = 0; i < 4; ++i) { st += redf[i]; ct += redi[i]; }
    out[0] = st / (float)(ct > 0 ? ct : 1);
  }
}

// ---------------------------------------------------------------- launch
extern "C" void kernel_launch(void* const* d_in, const int* in_sizes, int n_in,
                              void* d_out, int out_size, void* d_ws, size_t ws_size,
                              hipStream_t stream) {
  const float* student = (const float*)d_in[0];
  const float* W_s     = (const float*)d_in[1];
  const float* teacher = (const float*)d_in[2];
  const float* W_t     = (const float*)d_in[3];
  const int*   target  = (const int*)d_in[4];

  const int N  = in_sizes[4];            // 2048
  const int Hs = in_sizes[0] / N;        // 2048
  const int Ht = in_sizes[2] / N;        // 4096
  const int V  = in_sizes[1] / Hs;       // 32000

  char* ws = (char*)d_ws;
  size_t off = 0;
  auto alloc = [&](size_t bytes) -> void* {
    void* p = ws + off;
    off += (bytes + 255) & ~(size_t)255;
    return p;
  };
  uint8_t* Sf8  = (uint8_t*)alloc((size_t)N * Hs);
  uint8_t* Wsf8 = (uint8_t*)alloc((size_t)V * Hs);
  uint8_t* Tf8  = (uint8_t*)alloc((size_t)N * Ht);
  uint8_t* Wtf8 = (uint8_t*)alloc((size_t)V * Ht);
  uint16_t* slog = (uint16_t*)alloc((size_t)N * V * 2);
  uint16_t* tlog = (uint16_t*)alloc((size_t)N * V * 2);
  float* per_tok = (float*)alloc((size_t)N * sizeof(float));
  (void)ws_size;  // total ~465 MB

  f32_to_fp8_kernel<<<512, 256, 0, stream>>>(student, Sf8, N * Hs, 1.0f);
  f32_to_fp8_kernel<<<2048, 256, 0, stream>>>(W_s, Wsf8, V * Hs, WSCALE);
  f32_to_fp8_kernel<<<512, 256, 0, stream>>>(teacher, Tf8, N * Ht, 1.0f);
  f32_to_fp8_kernel<<<2048, 256, 0, stream>>>(W_t, Wtf8, V * Ht, WSCALE);

  const int RT = N / 256;   // 8
  const int CT = V / 256;   // 125
  // merged launch: teacher blocks first, student backfills the tail
  gemm_mx_kernel<<<2 * RT * CT, 512, 0, stream>>>(
      Tf8, Wtf8, tlog, Ht, Sf8, Wsf8, slog, Hs, V, RT, CT);

  jsd_rows_kernel<<<N, 256, 0, stream>>>(slog, tlog, per_tok, V);
  finalize_kernel<<<1, 256, 0, stream>>>(per_tok, target, (float*)d_out, N);
}

// Round 15
// 753.916 us; speedup vs baseline: 1.2979x; 1.2979x over previous
//
#include <hip/hip_runtime.h>
#include <hip/hip_bf16.h>
#include <hip/hip_fp8.h>
#include <stdint.h>

#define BETA 0.5f
#define IGNORE_INDEX (-100)
// Weights pre-scaled x64 into fp8 (avoids e4m3 subnormals for sigma~1/64);
// descale folded into the MX block-scale of B: 2^-6 (E8M0 0x79), exact.
#define WSCALE 64.0f
#define SCALE_ONE  0x7F7F7F7Fu  // E8M0 1.0 per byte
#define SCALE_D64  0x79797979u  // E8M0 2^-6 per byte

typedef float f32x4 __attribute__((ext_vector_type(4)));
typedef int   i32x4 __attribute__((ext_vector_type(4)));
typedef int   i32x8 __attribute__((ext_vector_type(8)));

// ---------------------------------------------------------------- converts
__global__ __launch_bounds__(256) void f32_to_fp8_kernel(
    const float* __restrict__ in, uint8_t* __restrict__ out, int n, float scale) {
  int i = (blockIdx.x * blockDim.x + threadIdx.x) * 8;
  const int stride = gridDim.x * blockDim.x * 8;
  for (; i < n; i += stride) {
    float4 v0 = *reinterpret_cast<const float4*>(in + i);
    float4 v1 = *reinterpret_cast<const float4*>(in + i + 4);
    const float f[8] = {v0.x, v0.y, v0.z, v0.w, v1.x, v1.y, v1.z, v1.w};
    union { uint8_t b[8]; uint2 u; } o;
#pragma unroll
    for (int j = 0; j < 8; ++j) {
      __hip_fp8_e4m3 h(f[j] * scale);
      o.b[j] = h.__x;
    }
    *reinterpret_cast<uint2*>(out + i) = o.u;
  }
}

// ---------------------------------------------------------------- GEMM (NT)
// C[n][v] = sum_k A[n][k] * (W[v][k]*64) * 2^-6, A/B fp8 e4m3, C bf16.
// MX K=128 MFMA on the r13 chassis: staging, 64-B-row layout, and the
// swizzle unit = (r&1)*4 + (kg^((r>>1)&3)) are r13-VERBATIM (measured 0
// bank conflicts).  K=128 comes from TILE PAIRING: 4 LDS buffers of 32 KB
// (tile&3); pair j reads tiles 2j (bufE) + 2j+1 (bufO); the MFMA operand
// is concat(quadE, quadO) -- a shared A/B k-permutation of the contiguous
// 128-k block, exact per r12's argument; r14 verified sigma_A == sigma_B
// (natural-order concat passed absmax 0) and the scale-builtin signature.
// Per-m A-reads inside the MFMA cluster keep live regs ~210 < 256 (r14's
// scratch spill fix).  Stages for pair j+2 issue mid-iteration (r7-proven
// placement); boundary vmcnt(8) leaves them in flight (T3+T4).  setprio
// (T5), XCD swizzle (T1).  LDS: 4 buf x (A 16K | B 16K) = 128 KiB.
// Merged launch: blocks [0,half) = teacher, [half,2*half) = student.

__global__ __launch_bounds__(512, 2) void gemm_mx2_kernel(
    const uint8_t* __restrict__ At, const uint8_t* __restrict__ Bt,
    uint16_t* __restrict__ Ct, int Kt,
    const uint8_t* __restrict__ As_, const uint8_t* __restrict__ Bs_,
    uint16_t* __restrict__ Cs, int Ks,
    int V, int RT, int CT) {
  __shared__ __align__(16) uint8_t lds[131072];

  const int half = RT * CT;
  const uint8_t *A, *B;
  uint16_t* C;
  int K, bidx = blockIdx.x;
  if (bidx < half) { A = At; B = Bt; C = Ct; K = Kt; }
  else             { A = As_; B = Bs_; C = Cs; K = Ks; bidx -= half; }

  int L = ((half & 7) == 0) ? ((bidx & 7) * (half >> 3) + (bidx >> 3)) : bidx;
  const int rt = L % RT;
  const int ct = L / RT;
  const int row0 = rt * 256;
  const int col0 = ct * 256;

  const int i  = threadIdx.x;      // 0..511
  const int w  = i >> 6;
  const int l  = i & 63;
  const int wl = l & 15;
  const int kg = l >> 4;           // quad selector 0..3
  const int wr = w >> 2;           // wave row 0..1 (128 out rows)
  const int wc = w & 3;            // wave col 0..3 (64 out cols)

  const int nJ = K >> 7;           // pairs of BK=64 tiles

  // ---- staging (r13 verbatim, buf = tile&3): thread i -> quad
  // (row rg = i>>2, phys pq = i&3) sources logical quad pq ^ ((rg>>1)&3).
  const int rg = i >> 2;           // 0..127
  const int pq = i & 3;
  const int qlog = pq ^ ((rg >> 1) & 3);
  const uint8_t* aSrc = A + (size_t)(row0 + rg) * K + qlog * 16;
  const uint8_t* bSrc = B + (size_t)(col0 + rg) * K + qlog * 16;
  uint8_t* ldsu = lds;

#define GL(srcp, dstp)                                                     \
  __builtin_amdgcn_global_load_lds(                                        \
      (const __attribute__((address_space(1))) void*)(srcp),               \
      (__attribute__((address_space(3))) void*)(dstp), 16, 0, 0)

#define STAGE_A(TT)                                                        \
  do {                                                                     \
    const uint8_t* _s = aSrc + (size_t)(TT) * 64;                          \
    uint8_t* _d = ldsu + (((TT) & 3) * 32768) + i * 16;                    \
    GL(_s, _d); GL(_s + (size_t)128 * K, _d + 8192);                       \
  } while (0)

#define STAGE_B(TT)                                                        \
  do {                                                                     \
    const uint8_t* _s = bSrc + (size_t)(TT) * 64;                          \
    uint8_t* _d = ldsu + (((TT) & 3) * 32768) + 16384 + i * 16;            \
    GL(_s, _d); GL(_s + (size_t)128 * K, _d + 8192);                       \
  } while (0)

  // ---- ds_read_b128 offsets (r13 verbatim): row r, phys quad =
  // kg ^ ((r>>1)&3); (r>>1)&3 == (wl>>1)&3 since row bases are mult of 16.
  int offA[8], offB[4];
  const int qsw = (kg ^ ((wl >> 1) & 3)) * 16;
#pragma unroll
  for (int m = 0; m < 8; ++m) {
    const int r = wr * 128 + m * 16 + wl;
    offA[m] = r * 64 + qsw;
  }
#pragma unroll
  for (int n = 0; n < 4; ++n) {
    const int r = wc * 64 + n * 16 + wl;
    offB[n] = 16384 + r * 64 + qsw;
  }

  f32x4 acc[8][4] = {};
  i32x8 bF[4];

  // ---- prologue: stage pairs 0,1 (tiles 0..3, 16 loads); wait pair 0
  STAGE_A(0); STAGE_B(0); STAGE_A(1); STAGE_B(1);
  if (nJ > 1) {
    STAGE_A(2); STAGE_B(2); STAGE_A(3); STAGE_B(3);
    asm volatile("s_waitcnt vmcnt(8)" ::: "memory");
  } else {
    asm volatile("s_waitcnt vmcnt(0)" ::: "memory");
  }
  __builtin_amdgcn_s_barrier();
  __builtin_amdgcn_sched_barrier(0);

  for (int j = 0; j < nJ; ++j) {
    const uint8_t* bufE = lds + ((2 * j) & 3) * 32768;
    const uint8_t* bufO = lds + ((2 * j + 1) & 3) * 32768;
    const bool stg2 = (j + 2) < nJ;

    // ---- read B fragments (8 b128) -> bF[0..3]
#pragma unroll
    for (int n = 0; n < 4; ++n) {
      i32x4 be = *reinterpret_cast<const i32x4*>(bufE + offB[n]);
      i32x4 bo = *reinterpret_cast<const i32x4*>(bufO + offB[n]);
      bF[n][0] = be[0]; bF[n][1] = be[1]; bF[n][2] = be[2]; bF[n][3] = be[3];
      bF[n][4] = bo[0]; bF[n][5] = bo[1]; bF[n][6] = bo[2]; bF[n][7] = bo[3];
    }

    // ---- stage pair j+2 (8 loads; overwrites pair-j buffers after our
    // reads; cross-wave safety = r7 pattern, barrier-started tile)
    if (stg2) {
      STAGE_A(2 * j + 4); STAGE_B(2 * j + 4);
      STAGE_A(2 * j + 5); STAGE_B(2 * j + 5);
    }

    // ---- MFMA cluster: per-m A-reads (keeps live regs ~210, no spill)
    __builtin_amdgcn_s_setprio(1);
#pragma unroll
    for (int m = 0; m < 8; ++m) {
      i32x4 ae = *reinterpret_cast<const i32x4*>(bufE + offA[m]);
      i32x4 ao = *reinterpret_cast<const i32x4*>(bufO + offA[m]);
      i32x8 aF;
      aF[0] = ae[0]; aF[1] = ae[1]; aF[2] = ae[2]; aF[3] = ae[3];
      aF[4] = ao[0]; aF[5] = ao[1]; aF[6] = ao[2]; aF[7] = ao[3];
#pragma unroll
      for (int n = 0; n < 4; ++n)
        acc[m][n] = __builtin_amdgcn_mfma_scale_f32_16x16x128_f8f6f4(
            aF, bF[n], acc[m][n], 0, 0, 0, SCALE_ONE, 0, SCALE_D64);
    }
    __builtin_amdgcn_s_setprio(0);

    // ---- boundary: counted vmcnt (pair j+1 landed, pair j+2 in flight)
    if (stg2) {
      asm volatile("s_waitcnt vmcnt(8)" ::: "memory");
    } else {
      asm volatile("s_waitcnt vmcnt(0)" ::: "memory");
    }
    __builtin_amdgcn_s_barrier();
    __builtin_amdgcn_sched_barrier(0);
  }

  // epilogue: C/D layout col=lane&15, row=(lane>>4)*4+reg (shape-determined)
#pragma unroll
  for (int mg = 0; mg < 8; ++mg)
#pragma unroll
    for (int ng = 0; ng < 4; ++ng)
#pragma unroll
      for (int r = 0; r < 4; ++r) {
        const int row = row0 + wr * 128 + mg * 16 + kg * 4 + r;
        const int col = col0 + wc * 64 + ng * 16 + wl;
        __hip_bfloat16 bv = __float2bfloat16(acc[mg][ng][r]);
        C[(size_t)row * V + col] = *reinterpret_cast<const uint16_t*>(&bv);
      }
#undef STAGE_A
#undef STAGE_B
#undef GL
}

// ---------------------------------------------------------------- JSD rows
__device__ __forceinline__ void unpack8(uint4 v, float* f) {
  uint32_t w[4] = {v.x, v.y, v.z, v.w};
#pragma unroll
  for (int j = 0; j < 4; ++j) {
    union { uint32_t u; float x; } lo, hi;
    lo.u = (w[j] & 0xffffu) << 16;
    hi.u = w[j] & 0xffff0000u;
    f[2 * j] = lo.x;
    f[2 * j + 1] = hi.x;
  }
}

__device__ __forceinline__ float blockReduce(float v, float* sh) {
#pragma unroll
  for (int o = 32; o >= 1; o >>= 1) v += __shfl_xor(v, o, 64);
  const int w = threadIdx.x >> 6;
  __syncthreads();
  if ((threadIdx.x & 63) == 0) sh[w] = v;
  __syncthreads();
  float r = sh[0];
#pragma unroll
  for (int i = 1; i < 4; ++i) r += sh[i];
  return r;
}

// online-LSE load pass (1 global sweep, fused max+sum) + 1 LDS JSD pass.
__global__ __launch_bounds__(256) void jsd_rows_kernel(
    const uint16_t* __restrict__ SL, const uint16_t* __restrict__ TL,
    float* __restrict__ per_tok, int V) {
  __shared__ __align__(16) uint16_t rowS[32000];
  __shared__ __align__(16) uint16_t rowT[32000];
  __shared__ float redM[2][4], redS[2][4], red[4];

  const int t = threadIdx.x;
  const int row = blockIdx.x;
  const uint4* gS = reinterpret_cast<const uint4*>(SL + (size_t)row * V);
  const uint4* gT = reinterpret_cast<const uint4*>(TL + (size_t)row * V);
  uint4* lS = reinterpret_cast<uint4*>(rowS);
  uint4* lT = reinterpret_cast<uint4*>(rowT);
  const int nvec = V >> 3;  // 4000

  float mS = -3.0e38f, sS = 0.f, mT = -3.0e38f, sT = 0.f;
  for (int i = t; i < nvec; i += 256) {
    uint4 vs = gS[i], vt = gT[i];
    lS[i] = vs; lT[i] = vt;
    float fs[8], ft[8];
    unpack8(vs, fs);
    unpack8(vt, ft);
    float vmS = fs[0], vmT = ft[0];
#pragma unroll
    for (int j = 1; j < 8; ++j) { vmS = fmaxf(vmS, fs[j]); vmT = fmaxf(vmT, ft[j]); }
    if (vmS > mS) { sS *= __expf(mS - vmS); mS = vmS; }
    if (vmT > mT) { sT *= __expf(mT - vmT); mT = vmT; }
#pragma unroll
    for (int j = 0; j < 8; ++j) { sS += __expf(fs[j] - mS); sT += __expf(ft[j] - mT); }
  }

#pragma unroll
  for (int o = 32; o >= 1; o >>= 1) {
    float mo = __shfl_xor(mS, o, 64), so = __shfl_xor(sS, o, 64);
    float mn = fmaxf(mS, mo);
    sS = sS * __expf(mS - mn) + so * __expf(mo - mn); mS = mn;
    mo = __shfl_xor(mT, o, 64); so = __shfl_xor(sT, o, 64);
    mn = fmaxf(mT, mo);
    sT = sT * __expf(mT - mn) + so * __expf(mo - mn); mT = mn;
  }
  const int wv = t >> 6;
  if ((t & 63) == 0) {
    redM[0][wv] = mS; redS[0][wv] = sS;
    redM[1][wv] = mT; redS[1][wv] = sT;
  }
  __syncthreads();   // covers (m,s) publication AND the LDS row writes
  float M0 = redM[0][0], S0 = redS[0][0];
  float M1 = redM[1][0], S1 = redS[1][0];
#pragma unroll
  for (int k = 1; k < 4; ++k) {
    float m2 = redM[0][k], s2 = redS[0][k];
    float mn = fmaxf(M0, m2);
    S0 = S0 * __expf(M0 - mn) + s2 * __expf(m2 - mn); M0 = mn;
    m2 = redM[1][k]; s2 = redS[1][k];
    mn = fmaxf(M1, m2);
    S1 = S1 * __expf(M1 - mn) + s2 * __expf(m2 - mn); M1 = mn;
  }
  const float lseS = M0 + __logf(S0);
  const float lseT = M1 + __logf(S1);

  float acc = 0.f;
  for (int i = t; i < nvec; i += 256) {
    float fs[8], ft[8];
    unpack8(lS[i], fs);
    unpack8(lT[i], ft);
#pragma unroll
    for (int j = 0; j < 8; ++j) {
      const float lq = fs[j] - lseS;
      const float lp = ft[j] - lseT;
      const float q = __expf(lq);
      const float p = __expf(lp);
      const float m = BETA * p + (1.f - BETA) * q;
      const float lm = __logf(m);
      acc += BETA * p * (lp - lm) + (1.f - BETA) * q * (lq - lm);
    }
  }
  acc = blockReduce(acc, red);
  if (t == 0) per_tok[row] = acc;
}

// ---------------------------------------------------------------- finalize
__global__ __launch_bounds__(256) void finalize_kernel(
    const float* __restrict__ per_tok, const int* __restrict__ tgt,
    float* __restrict__ out, int N) {
  __shared__ float redf[4];
  __shared__ int redi[4];
  float s = 0.f;
  int c = 0;
  for (int i = threadIdx.x; i < N; i += 256) {
    if (tgt[i] != IGNORE_INDEX) { s += per_tok[i]; c += 1; }
  }
#pragma unroll
  for (int o = 32; o >= 1; o >>= 1) {
    s += __shfl_xor(s, o, 64);
    c += __shfl_xor(c, o, 64);
  }
  const int w = threadIdx.x >> 6;
  if ((threadIdx.x & 63) == 0) { redf[w] = s; redi[w] = c; }
  __syncthreads();
  if (threadIdx.x == 0) {
    float st = 0.f;
    int ct = 0;
#pragma unroll
    for (int i = 0; i < 4; ++i) { st += redf[i]; ct += redi[i]; }
    out[0] = st / (float)(ct > 0 ? ct : 1);
  }
}

// ---------------------------------------------------------------- launch
extern "C" void kernel_launch(void* const* d_in, const int* in_sizes, int n_in,
                              void* d_out, int out_size, void* d_ws, size_t ws_size,
                              hipStream_t stream) {
  const float* student = (const float*)d_in[0];
  const float* W_s     = (const float*)d_in[1];
  const float* teacher = (const float*)d_in[2];
  const float* W_t     = (const float*)d_in[3];
  const int*   target  = (const int*)d_in[4];

  const int N  = in_sizes[4];            // 2048
  const int Hs = in_sizes[0] / N;        // 2048
  const int Ht = in_sizes[2] / N;        // 4096
  const int V  = in_sizes[1] / Hs;       // 32000

  char* ws = (char*)d_ws;
  size_t off = 0;
  auto alloc = [&](size_t bytes) -> void* {
    void* p = ws + off;
    off += (bytes + 255) & ~(size_t)255;
    return p;
  };
  uint8_t* Sf8  = (uint8_t*)alloc((size_t)N * Hs);
  uint8_t* Wsf8 = (uint8_t*)alloc((size_t)V * Hs);
  uint8_t* Tf8  = (uint8_t*)alloc((size_t)N * Ht);
  uint8_t* Wtf8 = (uint8_t*)alloc((size_t)V * Ht);
  uint16_t* slog = (uint16_t*)alloc((size_t)N * V * 2);
  uint16_t* tlog = (uint16_t*)alloc((size_t)N * V * 2);
  float* per_tok = (float*)alloc((size_t)N * sizeof(float));
  (void)ws_size;  // total ~465 MB

  f32_to_fp8_kernel<<<512, 256, 0, stream>>>(student, Sf8, N * Hs, 1.0f);
  f32_to_fp8_kernel<<<2048, 256, 0, stream>>>(W_s, Wsf8, V * Hs, WSCALE);
  f32_to_fp8_kernel<<<512, 256, 0, stream>>>(teacher, Tf8, N * Ht, 1.0f);
  f32_to_fp8_kernel<<<2048, 256, 0, stream>>>(W_t, Wtf8, V * Ht, WSCALE);

  const int RT = N / 256;   // 8
  const int CT = V / 256;   // 125
  // merged launch: teacher blocks first, student backfills the tail
  gemm_mx2_kernel<<<2 * RT * CT, 512, 0, stream>>>(
      Tf8, Wtf8, tlog, Ht, Sf8, Wsf8, slog, Hs, V, RT, CT);

  jsd_rows_kernel<<<N, 256, 0, stream>>>(slog, tlog, per_tok, V);
  finalize_kernel<<<1, 256, 0, stream>>>(per_tok, target, (float*)d_out, N);
}

// Round 16
// 744.696 us; speedup vs baseline: 1.3139x; 1.0124x over previous
//
#include <hip/hip_runtime.h>
#include <hip/hip_bf16.h>
#include <hip/hip_fp8.h>
#include <stdint.h>

#define BETA 0.5f
#define IGNORE_INDEX (-100)
// Weights pre-scaled x64 into fp8 (avoids e4m3 subnormals for sigma~1/64);
// descale folded into the MX block-scale of B: 2^-6 (E8M0 0x79), exact.
#define WSCALE 64.0f
#define SCALE_ONE  0x7F7F7F7Fu  // E8M0 1.0 per byte
#define SCALE_D64  0x79797979u  // E8M0 2^-6 per byte

typedef float f32x4 __attribute__((ext_vector_type(4)));
typedef int   i32x4 __attribute__((ext_vector_type(4)));
typedef int   i32x8 __attribute__((ext_vector_type(8)));

// ---------------------------------------------------------------- converts
// Hardware packed f32->fp8 (v_cvt_pk_fp8_f32); the __hip_fp8_e4m3 ctor's
// fast-path arch check may predate gfx950 and fall to software rounding.
__global__ __launch_bounds__(256) void f32_to_fp8_kernel(
    const float* __restrict__ in, uint8_t* __restrict__ out, int n, float scale) {
  int i = (blockIdx.x * blockDim.x + threadIdx.x) * 8;
  const int stride = gridDim.x * blockDim.x * 8;
  for (; i < n; i += stride) {
    float4 v0 = *reinterpret_cast<const float4*>(in + i);
    float4 v1 = *reinterpret_cast<const float4*>(in + i + 4);
    int lo = 0, hi = 0;
    lo = __builtin_amdgcn_cvt_pk_fp8_f32(v0.x * scale, v0.y * scale, lo, false);
    lo = __builtin_amdgcn_cvt_pk_fp8_f32(v0.z * scale, v0.w * scale, lo, true);
    hi = __builtin_amdgcn_cvt_pk_fp8_f32(v1.x * scale, v1.y * scale, hi, false);
    hi = __builtin_amdgcn_cvt_pk_fp8_f32(v1.z * scale, v1.w * scale, hi, true);
    uint2 o;
    o.x = (uint32_t)lo;
    o.y = (uint32_t)hi;
    *reinterpret_cast<uint2*>(out + i) = o;
  }
}

// ---------------------------------------------------------------- GEMM (NT)
// C[n][v] = sum_k A[n][k] * (W[v][k]*64) * 2^-6, A/B fp8 e4m3, C bf16.
// MX K=128 MFMA on the r13 chassis (r15), with PIPELINED A-READS (r16):
// r15's per-m A-reads sat inside the MFMA cluster, so each 4-MFMA group
// lgkm-waited on its own just-issued ds_reads -> wall = MFMA + LDS floors
// ADDED (5236 cyc/pair measured vs 5030 sum).  Now read A(m+1) before
// MFMA(m) with a 2-register rotation: ~120 cyc read latency hides under
// ~138 cyc of MFMA.  Source live set: 2 aF + 4 bF = 48 arch regs (no
// r14-style spill).  All else r15-verbatim: 64-B-row layout + swizzle
// unit (r&1)*4+(kg^((r>>1)&3)) [0 conflicts, 3x confirmed], tile-paired
// K=128 (4 buf x 32 KB), uniform-E8M0-scale MX (descale exact), counted
// vmcnt(8), setprio, XCD swizzle.
// Merged launch: blocks [0,half) = teacher, [half,2*half) = student.

__global__ __launch_bounds__(512, 2) void gemm_mx3_kernel(
    const uint8_t* __restrict__ At, const uint8_t* __restrict__ Bt,
    uint16_t* __restrict__ Ct, int Kt,
    const uint8_t* __restrict__ As_, const uint8_t* __restrict__ Bs_,
    uint16_t* __restrict__ Cs, int Ks,
    int V, int RT, int CT) {
  __shared__ __align__(16) uint8_t lds[131072];

  const int half = RT * CT;
  const uint8_t *A, *B;
  uint16_t* C;
  int K, bidx = blockIdx.x;
  if (bidx < half) { A = At; B = Bt; C = Ct; K = Kt; }
  else             { A = As_; B = Bs_; C = Cs; K = Ks; bidx -= half; }

  int L = ((half & 7) == 0) ? ((bidx & 7) * (half >> 3) + (bidx >> 3)) : bidx;
  const int rt = L % RT;
  const int ct = L / RT;
  const int row0 = rt * 256;
  const int col0 = ct * 256;

  const int i  = threadIdx.x;      // 0..511
  const int w  = i >> 6;
  const int l  = i & 63;
  const int wl = l & 15;
  const int kg = l >> 4;           // quad selector 0..3
  const int wr = w >> 2;           // wave row 0..1 (128 out rows)
  const int wc = w & 3;            // wave col 0..3 (64 out cols)

  const int nJ = K >> 7;           // pairs of BK=64 tiles

  // ---- staging (r13 verbatim, buf = tile&3): thread i -> quad
  // (row rg = i>>2, phys pq = i&3) sources logical quad pq ^ ((rg>>1)&3).
  const int rg = i >> 2;           // 0..127
  const int pq = i & 3;
  const int qlog = pq ^ ((rg >> 1) & 3);
  const uint8_t* aSrc = A + (size_t)(row0 + rg) * K + qlog * 16;
  const uint8_t* bSrc = B + (size_t)(col0 + rg) * K + qlog * 16;
  uint8_t* ldsu = lds;

#define GL(srcp, dstp)                                                     \
  __builtin_amdgcn_global_load_lds(                                        \
      (const __attribute__((address_space(1))) void*)(srcp),               \
      (__attribute__((address_space(3))) void*)(dstp), 16, 0, 0)

#define STAGE_A(TT)                                                        \
  do {                                                                     \
    const uint8_t* _s = aSrc + (size_t)(TT) * 64;                          \
    uint8_t* _d = ldsu + (((TT) & 3) * 32768) + i * 16;                    \
    GL(_s, _d); GL(_s + (size_t)128 * K, _d + 8192);                       \
  } while (0)

#define STAGE_B(TT)                                                        \
  do {                                                                     \
    const uint8_t* _s = bSrc + (size_t)(TT) * 64;                          \
    uint8_t* _d = ldsu + (((TT) & 3) * 32768) + 16384 + i * 16;            \
    GL(_s, _d); GL(_s + (size_t)128 * K, _d + 8192);                       \
  } while (0)

  // ---- ds_read_b128 offsets (r13 verbatim): row r, phys quad =
  // kg ^ ((r>>1)&3); (r>>1)&3 == (wl>>1)&3 since row bases are mult of 16.
  int offA[8], offB[4];
  const int qsw = (kg ^ ((wl >> 1) & 3)) * 16;
#pragma unroll
  for (int m = 0; m < 8; ++m) {
    const int r = wr * 128 + m * 16 + wl;
    offA[m] = r * 64 + qsw;
  }
#pragma unroll
  for (int n = 0; n < 4; ++n) {
    const int r = wc * 64 + n * 16 + wl;
    offB[n] = 16384 + r * 64 + qsw;
  }

  f32x4 acc[8][4] = {};
  i32x8 bF[4];

#define LOADA(dst, mm)                                                     \
  do {                                                                     \
    i32x4 _e = *reinterpret_cast<const i32x4*>(bufE + offA[mm]);           \
    i32x4 _o = *reinterpret_cast<const i32x4*>(bufO + offA[mm]);           \
    dst[0] = _e[0]; dst[1] = _e[1]; dst[2] = _e[2]; dst[3] = _e[3];        \
    dst[4] = _o[0]; dst[5] = _o[1]; dst[6] = _o[2]; dst[7] = _o[3];        \
  } while (0)

  // ---- prologue: stage pairs 0,1 (tiles 0..3, 16 loads); wait pair 0
  STAGE_A(0); STAGE_B(0); STAGE_A(1); STAGE_B(1);
  if (nJ > 1) {
    STAGE_A(2); STAGE_B(2); STAGE_A(3); STAGE_B(3);
    asm volatile("s_waitcnt vmcnt(8)" ::: "memory");
  } else {
    asm volatile("s_waitcnt vmcnt(0)" ::: "memory");
  }
  __builtin_amdgcn_s_barrier();
  __builtin_amdgcn_sched_barrier(0);

  for (int j = 0; j < nJ; ++j) {
    const uint8_t* bufE = lds + ((2 * j) & 3) * 32768;
    const uint8_t* bufO = lds + ((2 * j + 1) & 3) * 32768;
    const bool stg2 = (j + 2) < nJ;

    // ---- read B fragments (8 b128) -> bF[0..3]
#pragma unroll
    for (int n = 0; n < 4; ++n) {
      i32x4 be = *reinterpret_cast<const i32x4*>(bufE + offB[n]);
      i32x4 bo = *reinterpret_cast<const i32x4*>(bufO + offB[n]);
      bF[n][0] = be[0]; bF[n][1] = be[1]; bF[n][2] = be[2]; bF[n][3] = be[3];
      bF[n][4] = bo[0]; bF[n][5] = bo[1]; bF[n][6] = bo[2]; bF[n][7] = bo[3];
    }

    // ---- stage pair j+2 (8 loads; overwrites pair-j buffers after our
    // reads; cross-wave safety = r7 pattern, barrier-started tile)
    if (stg2) {
      STAGE_A(2 * j + 4); STAGE_B(2 * j + 4);
      STAGE_A(2 * j + 5); STAGE_B(2 * j + 5);
    }

    // ---- MFMA cluster with pipelined A-reads: read(m+1) before MFMA(m).
    __builtin_amdgcn_s_setprio(1);
    {
      i32x8 aCur, aNxt;
      LOADA(aCur, 0);
#pragma unroll
      for (int m = 0; m < 8; ++m) {
        if (m + 1 < 8) LOADA(aNxt, m + 1);
#pragma unroll
        for (int n = 0; n < 4; ++n)
          acc[m][n] = __builtin_amdgcn_mfma_scale_f32_16x16x128_f8f6f4(
              aCur, bF[n], acc[m][n], 0, 0, 0, SCALE_ONE, 0, SCALE_D64);
        aCur = aNxt;
      }
    }
    __builtin_amdgcn_s_setprio(0);

    // ---- boundary: counted vmcnt (pair j+1 landed, pair j+2 in flight)
    if (stg2) {
      asm volatile("s_waitcnt vmcnt(8)" ::: "memory");
    } else {
      asm volatile("s_waitcnt vmcnt(0)" ::: "memory");
    }
    __builtin_amdgcn_s_barrier();
    __builtin_amdgcn_sched_barrier(0);
  }

  // epilogue: C/D layout col=lane&15, row=(lane>>4)*4+reg (shape-determined)
#pragma unroll
  for (int mg = 0; mg < 8; ++mg)
#pragma unroll
    for (int ng = 0; ng < 4; ++ng)
#pragma unroll
      for (int r = 0; r < 4; ++r) {
        const int row = row0 + wr * 128 + mg * 16 + kg * 4 + r;
        const int col = col0 + wc * 64 + ng * 16 + wl;
        __hip_bfloat16 bv = __float2bfloat16(acc[mg][ng][r]);
        C[(size_t)row * V + col] = *reinterpret_cast<const uint16_t*>(&bv);
      }
#undef LOADA
#undef STAGE_A
#undef STAGE_B
#undef GL
}

// ---------------------------------------------------------------- JSD rows
__device__ __forceinline__ void unpack8(uint4 v, float* f) {
  uint32_t w[4] = {v.x, v.y, v.z, v.w};
#pragma unroll
  for (int j = 0; j < 4; ++j) {
    union { uint32_t u; float x; } lo, hi;
    lo.u = (w[j] & 0xffffu) << 16;
    hi.u = w[j] & 0xffff0000u;
    f[2 * j] = lo.x;
    f[2 * j + 1] = hi.x;
  }
}

__device__ __forceinline__ float blockReduce(float v, float* sh) {
#pragma unroll
  for (int o = 32; o >= 1; o >>= 1) v += __shfl_xor(v, o, 64);
  const int w = threadIdx.x >> 6;
  __syncthreads();
  if ((threadIdx.x & 63) == 0) sh[w] = v;
  __syncthreads();
  float r = sh[0];
#pragma unroll
  for (int i = 1; i < 4; ++i) r += sh[i];
  return r;
}

// online-LSE load pass (1 global sweep, fused max+sum) + 1 LDS JSD pass.
__global__ __launch_bounds__(256) void jsd_rows_kernel(
    const uint16_t* __restrict__ SL, const uint16_t* __restrict__ TL,
    float* __restrict__ per_tok, int V) {
  __shared__ __align__(16) uint16_t rowS[32000];
  __shared__ __align__(16) uint16_t rowT[32000];
  __shared__ float redM[2][4], redS[2][4], red[4];

  const int t = threadIdx.x;
  const int row = blockIdx.x;
  const uint4* gS = reinterpret_cast<const uint4*>(SL + (size_t)row * V);
  const uint4* gT = reinterpret_cast<const uint4*>(TL + (size_t)row * V);
  uint4* lS = reinterpret_cast<uint4*>(rowS);
  uint4* lT = reinterpret_cast<uint4*>(rowT);
  const int nvec = V >> 3;  // 4000

  float mS = -3.0e38f, sS = 0.f, mT = -3.0e38f, sT = 0.f;
  for (int i = t; i < nvec; i += 256) {
    uint4 vs = gS[i], vt = gT[i];
    lS[i] = vs; lT[i] = vt;
    float fs[8], ft[8];
    unpack8(vs, fs);
    unpack8(vt, ft);
    float vmS = fs[0], vmT = ft[0];
#pragma unroll
    for (int j = 1; j < 8; ++j) { vmS = fmaxf(vmS, fs[j]); vmT = fmaxf(vmT, ft[j]); }
    if (vmS > mS) { sS *= __expf(mS - vmS); mS = vmS; }
    if (vmT > mT) { sT *= __expf(mT - vmT); mT = vmT; }
#pragma unroll
    for (int j = 0; j < 8; ++j) { sS += __expf(fs[j] - mS); sT += __expf(ft[j] - mT); }
  }

#pragma unroll
  for (int o = 32; o >= 1; o >>= 1) {
    float mo = __shfl_xor(mS, o, 64), so = __shfl_xor(sS, o, 64);
    float mn = fmaxf(mS, mo);
    sS = sS * __expf(mS - mn) + so * __expf(mo - mn); mS = mn;
    mo = __shfl_xor(mT, o, 64); so = __shfl_xor(sT, o, 64);
    mn = fmaxf(mT, mo);
    sT = sT * __expf(mT - mn) + so * __expf(mo - mn); mT = mn;
  }
  const int wv = t >> 6;
  if ((t & 63) == 0) {
    redM[0][wv] = mS; redS[0][wv] = sS;
    redM[1][wv] = mT; redS[1][wv] = sT;
  }
  __syncthreads();   // covers (m,s) publication AND the LDS row writes
  float M0 = redM[0][0], S0 = redS[0][0];
  float M1 = redM[1][0], S1 = redS[1][0];
#pragma unroll
  for (int k = 1; k < 4; ++k) {
    float m2 = redM[0][k], s2 = redS[0][k];
    float mn = fmaxf(M0, m2);
    S0 = S0 * __expf(M0 - mn) + s2 * __expf(m2 - mn); M0 = mn;
    m2 = redM[1][k]; s2 = redS[1][k];
    mn = fmaxf(M1, m2);
    S1 = S1 * __expf(M1 - mn) + s2 * __expf(m2 - mn); M1 = mn;
  }
  const float lseS = M0 + __logf(S0);
  const float lseT = M1 + __logf(S1);

  float acc = 0.f;
  for (int i = t; i < nvec; i += 256) {
    float fs[8], ft[8];
    unpack8(lS[i], fs);
    unpack8(lT[i], ft);
#pragma unroll
    for (int j = 0; j < 8; ++j) {
      const float lq = fs[j] - lseS;
      const float lp = ft[j] - lseT;
      const float q = __expf(lq);
      const float p = __expf(lp);
      const float m = BETA * p + (1.f - BETA) * q;
      const float lm = __logf(m);
      acc += BETA * p * (lp - lm) + (1.f - BETA) * q * (lq - lm);
    }
  }
  acc = blockReduce(acc, red);
  if (t == 0) per_tok[row] = acc;
}

// ---------------------------------------------------------------- finalize
__global__ __launch_bounds__(256) void finalize_kernel(
    const float* __restrict__ per_tok, const int* __restrict__ tgt,
    float* __restrict__ out, int N) {
  __shared__ float redf[4];
  __shared__ int redi[4];
  float s = 0.f;
  int c = 0;
  for (int i = threadIdx.x; i < N; i += 256) {
    if (tgt[i] != IGNORE_INDEX) { s += per_tok[i]; c += 1; }
  }
#pragma unroll
  for (int o = 32; o >= 1; o >>= 1) {
    s += __shfl_xor(s, o, 64);
    c += __shfl_xor(c, o, 64);
  }
  const int w = threadIdx.x >> 6;
  if ((threadIdx.x & 63) == 0) { redf[w] = s; redi[w] = c; }
  __syncthreads();
  if (threadIdx.x == 0) {
    float st = 0.f;
    int ct = 0;
#pragma unroll
    for (int i = 0; i < 4; ++i) { st += redf[i]; ct += redi[i]; }
    out[0] = st / (float)(ct > 0 ? ct : 1);
  }
}

// ---------------------------------------------------------------- launch
extern "C" void kernel_launch(void* const* d_in, const int* in_sizes, int n_in,
                              void* d_out, int out_size, void* d_ws, size_t ws_size,
                              hipStream_t stream) {
  const float* student = (const float*)d_in[0];
  const float* W_s     = (const float*)d_in[1];
  const float* teacher = (const float*)d_in[2];
  const float* W_t     = (const float*)d_in[3];
  const int*   target  = (const int*)d_in[4];

  const int N  = in_sizes[4];            // 2048
  const int Hs = in_sizes[0] / N;        // 2048
  const int Ht = in_sizes[2] / N;        // 4096
  const int V  = in_sizes[1] / Hs;       // 32000

  char* ws = (char*)d_ws;
  size_t off = 0;
  auto alloc = [&](size_t bytes) -> void* {
    void* p = ws + off;
    off += (bytes + 255) & ~(size_t)255;
    return p;
  };
  uint8_t* Sf8  = (uint8_t*)alloc((size_t)N * Hs);
  uint8_t* Wsf8 = (uint8_t*)alloc((size_t)V * Hs);
  uint8_t* Tf8  = (uint8_t*)alloc((size_t)N * Ht);
  uint8_t* Wtf8 = (uint8_t*)alloc((size_t)V * Ht);
  uint16_t* slog = (uint16_t*)alloc((size_t)N * V * 2);
  uint16_t* tlog = (uint16_t*)alloc((size_t)N * V * 2);
  float* per_tok = (float*)alloc((size_t)N * sizeof(float));
  (void)ws_size;  // total ~465 MB

  f32_to_fp8_kernel<<<512, 256, 0, stream>>>(student, Sf8, N * Hs, 1.0f);
  f32_to_fp8_kernel<<<2048, 256, 0, stream>>>(W_s, Wsf8, V * Hs, WSCALE);
  f32_to_fp8_kernel<<<512, 256, 0, stream>>>(teacher, Tf8, N * Ht, 1.0f);
  f32_to_fp8_kernel<<<2048, 256, 0, stream>>>(W_t, Wtf8, V * Ht, WSCALE);

  const int RT = N / 256;   // 8
  const int CT = V / 256;   // 125
  // merged launch: teacher blocks first, student backfills the tail
  gemm_mx3_kernel<<<2 * RT * CT, 512, 0, stream>>>(
      Tf8, Wtf8, tlog, Ht, Sf8, Wsf8, slog, Hs, V, RT, CT);

  jsd_rows_kernel<<<N, 256, 0, stream>>>(slog, tlog, per_tok, V);
  finalize_kernel<<<1, 256, 0, stream>>>(per_tok, target, (float*)d_out, N);
}

// Round 17
// 729.081 us; speedup vs baseline: 1.3421x; 1.0214x over previous
//
#include <hip/hip_runtime.h>
#include <hip/hip_bf16.h>
#include <hip/hip_fp8.h>
#include <stdint.h>

#define BETA 0.5f
#define IGNORE_INDEX (-100)
// Weights pre-scaled x64 into fp8 (avoids e4m3 subnormals for sigma~1/64);
// descale folded into the MX block-scale of B: 2^-6 (E8M0 0x79), exact.
#define WSCALE 64.0f
#define SCALE_ONE  0x7F7F7F7Fu  // E8M0 1.0 per byte
#define SCALE_D64  0x79797979u  // E8M0 2^-6 per byte

typedef float f32x4 __attribute__((ext_vector_type(4)));
typedef int   i32x4 __attribute__((ext_vector_type(4)));
typedef int   i32x8 __attribute__((ext_vector_type(8)));

// ---------------------------------------------------------------- converts
// Single fused launch for all 4 arrays (all sizes divisible by 4096 floats):
// 16 floats/thread, no loops, no tails.  Per block: 4096 floats; thread t
// handles offsets t*4 + k*1024 (k=0..3) -> every float4 load and u32 store
// is wave-contiguous (1 KB / 256 B per wave per instr).  4 independent
// loads issued up-front (ILP).  Same v_cvt_pk_fp8_f32 math as r16.
__global__ __launch_bounds__(256) void fused_cvt_kernel(
    const float* __restrict__ s0, uint8_t* __restrict__ d0, int e0,
    const float* __restrict__ s1, uint8_t* __restrict__ d1, int e1,
    const float* __restrict__ s2, uint8_t* __restrict__ d2, int e2,
    const float* __restrict__ s3, uint8_t* __restrict__ d3) {
  int b = blockIdx.x;
  const float* src;
  uint8_t* dst;
  float scale;
  if (b < e0)      { src = s0; dst = d0; scale = 1.0f;   }
  else if (b < e1) { src = s1; dst = d1; scale = WSCALE; b -= e0; }
  else if (b < e2) { src = s2; dst = d2; scale = 1.0f;   b -= e1; }
  else             { src = s3; dst = d3; scale = WSCALE; b -= e2; }

  const size_t blk = (size_t)b * 4096;
  const int t4 = threadIdx.x * 4;
  // 4 independent wave-contiguous float4 loads
  float4 v0 = *reinterpret_cast<const float4*>(src + blk + t4);
  float4 v1 = *reinterpret_cast<const float4*>(src + blk + t4 + 1024);
  float4 v2 = *reinterpret_cast<const float4*>(src + blk + t4 + 2048);
  float4 v3 = *reinterpret_cast<const float4*>(src + blk + t4 + 3072);

  auto pack4 = [&scale](const float4& v) -> uint32_t {
    int r = 0;
    r = __builtin_amdgcn_cvt_pk_fp8_f32(v.x * scale, v.y * scale, r, false);
    r = __builtin_amdgcn_cvt_pk_fp8_f32(v.z * scale, v.w * scale, r, true);
    return (uint32_t)r;
  };
  *reinterpret_cast<uint32_t*>(dst + blk + t4)        = pack4(v0);
  *reinterpret_cast<uint32_t*>(dst + blk + t4 + 1024) = pack4(v1);
  *reinterpret_cast<uint32_t*>(dst + blk + t4 + 2048) = pack4(v2);
  *reinterpret_cast<uint32_t*>(dst + blk + t4 + 3072) = pack4(v3);
}

// ---------------------------------------------------------------- GEMM (NT)
// r16 VERBATIM (best measured: 398 us, MfmaUtil 45%, 0 conflicts).
// C[n][v] = sum_k A[n][k] * (W[v][k]*64) * 2^-6, A/B fp8 e4m3, C bf16.
// MX K=128 (tile-paired, 4 buf x 32 KB), r13 64-B-row swizzle (0 conflicts,
// 3x confirmed), pipelined A-reads, counted vmcnt(8), setprio, XCD swizzle.
__global__ __launch_bounds__(512, 2) void gemm_mx3_kernel(
    const uint8_t* __restrict__ At, const uint8_t* __restrict__ Bt,
    uint16_t* __restrict__ Ct, int Kt,
    const uint8_t* __restrict__ As_, const uint8_t* __restrict__ Bs_,
    uint16_t* __restrict__ Cs, int Ks,
    int V, int RT, int CT) {
  __shared__ __align__(16) uint8_t lds[131072];

  const int half = RT * CT;
  const uint8_t *A, *B;
  uint16_t* C;
  int K, bidx = blockIdx.x;
  if (bidx < half) { A = At; B = Bt; C = Ct; K = Kt; }
  else             { A = As_; B = Bs_; C = Cs; K = Ks; bidx -= half; }

  int L = ((half & 7) == 0) ? ((bidx & 7) * (half >> 3) + (bidx >> 3)) : bidx;
  const int rt = L % RT;
  const int ct = L / RT;
  const int row0 = rt * 256;
  const int col0 = ct * 256;

  const int i  = threadIdx.x;      // 0..511
  const int w  = i >> 6;
  const int l  = i & 63;
  const int wl = l & 15;
  const int kg = l >> 4;           // quad selector 0..3
  const int wr = w >> 2;           // wave row 0..1 (128 out rows)
  const int wc = w & 3;            // wave col 0..3 (64 out cols)

  const int nJ = K >> 7;           // pairs of BK=64 tiles

  const int rg = i >> 2;           // 0..127
  const int pq = i & 3;
  const int qlog = pq ^ ((rg >> 1) & 3);
  const uint8_t* aSrc = A + (size_t)(row0 + rg) * K + qlog * 16;
  const uint8_t* bSrc = B + (size_t)(col0 + rg) * K + qlog * 16;
  uint8_t* ldsu = lds;

#define GL(srcp, dstp)                                                     \
  __builtin_amdgcn_global_load_lds(                                        \
      (const __attribute__((address_space(1))) void*)(srcp),               \
      (__attribute__((address_space(3))) void*)(dstp), 16, 0, 0)

#define STAGE_A(TT)                                                        \
  do {                                                                     \
    const uint8_t* _s = aSrc + (size_t)(TT) * 64;                          \
    uint8_t* _d = ldsu + (((TT) & 3) * 32768) + i * 16;                    \
    GL(_s, _d); GL(_s + (size_t)128 * K, _d + 8192);                       \
  } while (0)

#define STAGE_B(TT)                                                        \
  do {                                                                     \
    const uint8_t* _s = bSrc + (size_t)(TT) * 64;                          \
    uint8_t* _d = ldsu + (((TT) & 3) * 32768) + 16384 + i * 16;            \
    GL(_s, _d); GL(_s + (size_t)128 * K, _d + 8192);                       \
  } while (0)

  int offA[8], offB[4];
  const int qsw = (kg ^ ((wl >> 1) & 3)) * 16;
#pragma unroll
  for (int m = 0; m < 8; ++m) {
    const int r = wr * 128 + m * 16 + wl;
    offA[m] = r * 64 + qsw;
  }
#pragma unroll
  for (int n = 0; n < 4; ++n) {
    const int r = wc * 64 + n * 16 + wl;
    offB[n] = 16384 + r * 64 + qsw;
  }

  f32x4 acc[8][4] = {};
  i32x8 bF[4];

#define LOADA(dst, mm)                                                     \
  do {                                                                     \
    i32x4 _e = *reinterpret_cast<const i32x4*>(bufE + offA[mm]);           \
    i32x4 _o = *reinterpret_cast<const i32x4*>(bufO + offA[mm]);           \
    dst[0] = _e[0]; dst[1] = _e[1]; dst[2] = _e[2]; dst[3] = _e[3];        \
    dst[4] = _o[0]; dst[5] = _o[1]; dst[6] = _o[2]; dst[7] = _o[3];        \
  } while (0)

  STAGE_A(0); STAGE_B(0); STAGE_A(1); STAGE_B(1);
  if (nJ > 1) {
    STAGE_A(2); STAGE_B(2); STAGE_A(3); STAGE_B(3);
    asm volatile("s_waitcnt vmcnt(8)" ::: "memory");
  } else {
    asm volatile("s_waitcnt vmcnt(0)" ::: "memory");
  }
  __builtin_amdgcn_s_barrier();
  __builtin_amdgcn_sched_barrier(0);

  for (int j = 0; j < nJ; ++j) {
    const uint8_t* bufE = lds + ((2 * j) & 3) * 32768;
    const uint8_t* bufO = lds + ((2 * j + 1) & 3) * 32768;
    const bool stg2 = (j + 2) < nJ;

#pragma unroll
    for (int n = 0; n < 4; ++n) {
      i32x4 be = *reinterpret_cast<const i32x4*>(bufE + offB[n]);
      i32x4 bo = *reinterpret_cast<const i32x4*>(bufO + offB[n]);
      bF[n][0] = be[0]; bF[n][1] = be[1]; bF[n][2] = be[2]; bF[n][3] = be[3];
      bF[n][4] = bo[0]; bF[n][5] = bo[1]; bF[n][6] = bo[2]; bF[n][7] = bo[3];
    }

    if (stg2) {
      STAGE_A(2 * j + 4); STAGE_B(2 * j + 4);
      STAGE_A(2 * j + 5); STAGE_B(2 * j + 5);
    }

    __builtin_amdgcn_s_setprio(1);
    {
      i32x8 aCur, aNxt;
      LOADA(aCur, 0);
#pragma unroll
      for (int m = 0; m < 8; ++m) {
        if (m + 1 < 8) LOADA(aNxt, m + 1);
#pragma unroll
        for (int n = 0; n < 4; ++n)
          acc[m][n] = __builtin_amdgcn_mfma_scale_f32_16x16x128_f8f6f4(
              aCur, bF[n], acc[m][n], 0, 0, 0, SCALE_ONE, 0, SCALE_D64);
        aCur = aNxt;
      }
    }
    __builtin_amdgcn_s_setprio(0);

    if (stg2) {
      asm volatile("s_waitcnt vmcnt(8)" ::: "memory");
    } else {
      asm volatile("s_waitcnt vmcnt(0)" ::: "memory");
    }
    __builtin_amdgcn_s_barrier();
    __builtin_amdgcn_sched_barrier(0);
  }

#pragma unroll
  for (int mg = 0; mg < 8; ++mg)
#pragma unroll
    for (int ng = 0; ng < 4; ++ng)
#pragma unroll
      for (int r = 0; r < 4; ++r) {
        const int row = row0 + wr * 128 + mg * 16 + kg * 4 + r;
        const int col = col0 + wc * 64 + ng * 16 + wl;
        __hip_bfloat16 bv = __float2bfloat16(acc[mg][ng][r]);
        C[(size_t)row * V + col] = *reinterpret_cast<const uint16_t*>(&bv);
      }
#undef LOADA
#undef STAGE_A
#undef STAGE_B
#undef GL
}

// ---------------------------------------------------------------- JSD rows
__device__ __forceinline__ void unpack8(uint4 v, float* f) {
  uint32_t w[4] = {v.x, v.y, v.z, v.w};
#pragma unroll
  for (int j = 0; j < 4; ++j) {
    union { uint32_t u; float x; } lo, hi;
    lo.u = (w[j] & 0xffffu) << 16;
    hi.u = w[j] & 0xffff0000u;
    f[2 * j] = lo.x;
    f[2 * j + 1] = hi.x;
  }
}

__device__ __forceinline__ float blockReduce(float v, float* sh) {
#pragma unroll
  for (int o = 32; o >= 1; o >>= 1) v += __shfl_xor(v, o, 64);
  const int w = threadIdx.x >> 6;
  __syncthreads();
  if ((threadIdx.x & 63) == 0) sh[w] = v;
  __syncthreads();
  float r = sh[0];
#pragma unroll
  for (int i = 1; i < 4; ++i) r += sh[i];
  return r;
}

// online-LSE load pass (1 global sweep, fused max+sum) + 1 LDS JSD pass.
__global__ __launch_bounds__(256) void jsd_rows_kernel(
    const uint16_t* __restrict__ SL, const uint16_t* __restrict__ TL,
    float* __restrict__ per_tok, int V) {
  __shared__ __align__(16) uint16_t rowS[32000];
  __shared__ __align__(16) uint16_t rowT[32000];
  __shared__ float redM[2][4], redS[2][4], red[4];

  const int t = threadIdx.x;
  const int row = blockIdx.x;
  const uint4* gS = reinterpret_cast<const uint4*>(SL + (size_t)row * V);
  const uint4* gT = reinterpret_cast<const uint4*>(TL + (size_t)row * V);
  uint4* lS = reinterpret_cast<uint4*>(rowS);
  uint4* lT = reinterpret_cast<uint4*>(rowT);
  const int nvec = V >> 3;  // 4000

  float mS = -3.0e38f, sS = 0.f, mT = -3.0e38f, sT = 0.f;
  for (int i = t; i < nvec; i += 256) {
    uint4 vs = gS[i], vt = gT[i];
    lS[i] = vs; lT[i] = vt;
    float fs[8], ft[8];
    unpack8(vs, fs);
    unpack8(vt, ft);
    float vmS = fs[0], vmT = ft[0];
#pragma unroll
    for (int j = 1; j < 8; ++j) { vmS = fmaxf(vmS, fs[j]); vmT = fmaxf(vmT, ft[j]); }
    if (vmS > mS) { sS *= __expf(mS - vmS); mS = vmS; }
    if (vmT > mT) { sT *= __expf(mT - vmT); mT = vmT; }
#pragma unroll
    for (int j = 0; j < 8; ++j) { sS += __expf(fs[j] - mS); sT += __expf(ft[j] - mT); }
  }

#pragma unroll
  for (int o = 32; o >= 1; o >>= 1) {
    float mo = __shfl_xor(mS, o, 64), so = __shfl_xor(sS, o, 64);
    float mn = fmaxf(mS, mo);
    sS = sS * __expf(mS - mn) + so * __expf(mo - mn); mS = mn;
    mo = __shfl_xor(mT, o, 64); so = __shfl_xor(sT, o, 64);
    mn = fmaxf(mT, mo);
    sT = sT * __expf(mT - mn) + so * __expf(mo - mn); mT = mn;
  }
  const int wv = t >> 6;
  if ((t & 63) == 0) {
    redM[0][wv] = mS; redS[0][wv] = sS;
    redM[1][wv] = mT; redS[1][wv] = sT;
  }
  __syncthreads();   // covers (m,s) publication AND the LDS row writes
  float M0 = redM[0][0], S0 = redS[0][0];
  float M1 = redM[1][0], S1 = redS[1][0];
#pragma unroll
  for (int k = 1; k < 4; ++k) {
    float m2 = redM[0][k], s2 = redS[0][k];
    float mn = fmaxf(M0, m2);
    S0 = S0 * __expf(M0 - mn) + s2 * __expf(m2 - mn); M0 = mn;
    m2 = redM[1][k]; s2 = redS[1][k];
    mn = fmaxf(M1, m2);
    S1 = S1 * __expf(M1 - mn) + s2 * __expf(m2 - mn); M1 = mn;
  }
  const float lseS = M0 + __logf(S0);
  const float lseT = M1 + __logf(S1);

  float acc = 0.f;
  for (int i = t; i < nvec; i += 256) {
    float fs[8], ft[8];
    unpack8(lS[i], fs);
    unpack8(lT[i], ft);
#pragma unroll
    for (int j = 0; j < 8; ++j) {
      const float lq = fs[j] - lseS;
      const float lp = ft[j] - lseT;
      const float q = __expf(lq);
      const float p = __expf(lp);
      const float m = BETA * p + (1.f - BETA) * q;
      const float lm = __logf(m);
      acc += BETA * p * (lp - lm) + (1.f - BETA) * q * (lq - lm);
    }
  }
  acc = blockReduce(acc, red);
  if (t == 0) per_tok[row] = acc;
}

// ---------------------------------------------------------------- finalize
__global__ __launch_bounds__(256) void finalize_kernel(
    const float* __restrict__ per_tok, const int* __restrict__ tgt,
    float* __restrict__ out, int N) {
  __shared__ float redf[4];
  __shared__ int redi[4];
  float s = 0.f;
  int c = 0;
  for (int i = threadIdx.x; i < N; i += 256) {
    if (tgt[i] != IGNORE_INDEX) { s += per_tok[i]; c += 1; }
  }
#pragma unroll
  for (int o = 32; o >= 1; o >>= 1) {
    s += __shfl_xor(s, o, 64);
    c += __shfl_xor(c, o, 64);
  }
  const int w = threadIdx.x >> 6;
  if ((threadIdx.x & 63) == 0) { redf[w] = s; redi[w] = c; }
  __syncthreads();
  if (threadIdx.x == 0) {
    float st = 0.f;
    int ct = 0;
#pragma unroll
    for (int i = 0; i < 4; ++i) { st += redf[i]; ct += redi[i]; }
    out[0] = st / (float)(ct > 0 ? ct : 1);
  }
}

// ---------------------------------------------------------------- launch
extern "C" void kernel_launch(void* const* d_in, const int* in_sizes, int n_in,
                              void* d_out, int out_size, void* d_ws, size_t ws_size,
                              hipStream_t stream) {
  const float* student = (const float*)d_in[0];
  const float* W_s     = (const float*)d_in[1];
  const float* teacher = (const float*)d_in[2];
  const float* W_t     = (const float*)d_in[3];
  const int*   target  = (const int*)d_in[4];

  const int N  = in_sizes[4];            // 2048
  const int Hs = in_sizes[0] / N;        // 2048
  const int Ht = in_sizes[2] / N;        // 4096
  const int V  = in_sizes[1] / Hs;       // 32000

  char* ws = (char*)d_ws;
  size_t off = 0;
  auto alloc = [&](size_t bytes) -> void* {
    void* p = ws + off;
    off += (bytes + 255) & ~(size_t)255;
    return p;
  };
  uint8_t* Sf8  = (uint8_t*)alloc((size_t)N * Hs);
  uint8_t* Wsf8 = (uint8_t*)alloc((size_t)V * Hs);
  uint8_t* Tf8  = (uint8_t*)alloc((size_t)N * Ht);
  uint8_t* Wtf8 = (uint8_t*)alloc((size_t)V * Ht);
  uint16_t* slog = (uint16_t*)alloc((size_t)N * V * 2);
  uint16_t* tlog = (uint16_t*)alloc((size_t)N * V * 2);
  float* per_tok = (float*)alloc((size_t)N * sizeof(float));
  (void)ws_size;  // total ~465 MB

  // fused convert: one launch, 4096 floats/block (all sizes divide evenly)
  const int b0 = (N * Hs) / 4096;               // 1024
  const int b1 = b0 + (V * Hs) / 4096;          // +16000
  const int b2 = b1 + (N * Ht) / 4096;          // +2048
  const int bT = b2 + (V * Ht) / 4096;          // +32000 = 51072
  fused_cvt_kernel<<<bT, 256, 0, stream>>>(
      student, Sf8, b0, W_s, Wsf8, b1, teacher, Tf8, b2, W_t, Wtf8);

  const int RT = N / 256;   // 8
  const int CT = V / 256;   // 125
  // merged launch: teacher blocks first, student backfills the tail
  gemm_mx3_kernel<<<2 * RT * CT, 512, 0, stream>>>(
      Tf8, Wtf8, tlog, Ht, Sf8, Wsf8, slog, Hs, V, RT, CT);

  jsd_rows_kernel<<<N, 256, 0, stream>>>(slog, tlog, per_tok, V);
  finalize_kernel<<<1, 256, 0, stream>>>(per_tok, target, (float*)d_out, N);
}

// Round 18
// 725.753 us; speedup vs baseline: 1.3482x; 1.0046x over previous
//
#include <hip/hip_runtime.h>
#include <hip/hip_bf16.h>
#include <hip/hip_fp8.h>
#include <stdint.h>

#define BETA 0.5f
#define IGNORE_INDEX (-100)
// Weights pre-scaled x64 into fp8 (avoids e4m3 subnormals for sigma~1/64);
// descale folded into the MX block-scale of B: 2^-6 (E8M0 0x79), exact.
#define WSCALE 64.0f
#define SCALE_ONE  0x7F7F7F7Fu  // E8M0 1.0 per byte
#define SCALE_D64  0x79797979u  // E8M0 2^-6 per byte

typedef float f32x4 __attribute__((ext_vector_type(4)));
typedef int   i32x4 __attribute__((ext_vector_type(4)));
typedef int   i32x8 __attribute__((ext_vector_type(8)));

// ---------------------------------------------------------------- converts
// Grid-stride fused convert, chunk = 8192 floats (all array boundaries are
// even multiples of 4096 floats -> chunks never straddle arrays).  Per
// iter: 8 independent NONTEMPORAL f32x4 loads (fp32 stream has zero reuse;
// keep it out of L2 so the fp8 outputs stay cached for the GEMM), 8 u32
// wave-contiguous stores.  e* in chunk units.
__global__ __launch_bounds__(256) void fused_cvt_kernel(
    const float* __restrict__ s0, uint8_t* __restrict__ d0, int e0,
    const float* __restrict__ s1, uint8_t* __restrict__ d1, int e1,
    const float* __restrict__ s2, uint8_t* __restrict__ d2, int e2,
    const float* __restrict__ s3, uint8_t* __restrict__ d3, int eT) {
  for (int c = blockIdx.x; c < eT; c += gridDim.x) {
    const float* src;
    uint8_t* dst;
    float scale;
    int cb = c;
    if (c < e0)      { src = s0; dst = d0; scale = 1.0f;   }
    else if (c < e1) { src = s1; dst = d1; scale = WSCALE; cb -= e0; }
    else if (c < e2) { src = s2; dst = d2; scale = 1.0f;   cb -= e1; }
    else             { src = s3; dst = d3; scale = WSCALE; cb -= e2; }

    const size_t base = (size_t)cb * 8192 + threadIdx.x * 4;
    f32x4 v[8];
#pragma unroll
    for (int k = 0; k < 8; ++k)
      v[k] = __builtin_nontemporal_load(
          reinterpret_cast<const f32x4*>(src + base + k * 1024));
#pragma unroll
    for (int k = 0; k < 8; ++k) {
      int r = 0;
      r = __builtin_amdgcn_cvt_pk_fp8_f32(v[k][0] * scale, v[k][1] * scale, r, false);
      r = __builtin_amdgcn_cvt_pk_fp8_f32(v[k][2] * scale, v[k][3] * scale, r, true);
      *reinterpret_cast<uint32_t*>(dst + base + k * 1024) = (uint32_t)r;
    }
  }
}

// ---------------------------------------------------------------- GEMM (NT)
// C[n][v] = sum_k A[n][k] * (W[v][k]*64) * 2^-6, A/B fp8 e4m3, C bf16.
// MX K=128 (tile-paired), r13 64-B-row swizzle (0 conflicts, 3x confirmed),
// pipelined A-reads (r16).  r18: RACE-FREE DEPTH-1 PAIR STAGING -- two
// 64 KB slots; iter j reads slot j&1 and stages pair j+1 into the OTHER
// slot, which holds pair j-1: fully consumed and barrier-retired before
// iter j began (r15-r17's depth-2 wrote the slot being read, guarded only
// by load-return latency).  Boundary: vmcnt(0) (stage issued ~2500 cyc
// earlier -> free) + barrier.  setprio (T5), XCD swizzle (T1).
// Slot layout: A_E@0  A_O@16K  B_E@32K  B_O@48K  (16 KB each).
// Merged launch: blocks [0,half) = teacher, [half,2*half) = student.

__global__ __launch_bounds__(512, 2) void gemm_mx4_kernel(
    const uint8_t* __restrict__ At, const uint8_t* __restrict__ Bt,
    uint16_t* __restrict__ Ct, int Kt,
    const uint8_t* __restrict__ As_, const uint8_t* __restrict__ Bs_,
    uint16_t* __restrict__ Cs, int Ks,
    int V, int RT, int CT) {
  __shared__ __align__(16) uint8_t lds[131072];

  const int half = RT * CT;
  const uint8_t *A, *B;
  uint16_t* C;
  int K, bidx = blockIdx.x;
  if (bidx < half) { A = At; B = Bt; C = Ct; K = Kt; }
  else             { A = As_; B = Bs_; C = Cs; K = Ks; bidx -= half; }

  int L = ((half & 7) == 0) ? ((bidx & 7) * (half >> 3) + (bidx >> 3)) : bidx;
  const int rt = L % RT;
  const int ct = L / RT;
  const int row0 = rt * 256;
  const int col0 = ct * 256;

  const int i  = threadIdx.x;      // 0..511
  const int w  = i >> 6;
  const int l  = i & 63;
  const int wl = l & 15;
  const int kg = l >> 4;           // quad selector 0..3
  const int wr = w >> 2;           // wave row 0..1 (128 out rows)
  const int wc = w & 3;            // wave col 0..3 (64 out cols)

  const int nJ = K >> 7;           // pairs of BK=64 tiles

  // staging: thread i -> quad (row rg = i>>2, phys pq = i&3), logical quad
  // pq ^ ((rg>>1)&3); rows rg and rg+128 share the XOR term.
  const int rg = i >> 2;           // 0..127
  const int pq = i & 3;
  const int qlog = pq ^ ((rg >> 1) & 3);
  const uint8_t* aSrc = A + (size_t)(row0 + rg) * K + qlog * 16;
  const uint8_t* bSrc = B + (size_t)(col0 + rg) * K + qlog * 16;
  uint8_t* ldsu = lds;

#define GL(srcp, dstp)                                                     \
  __builtin_amdgcn_global_load_lds(                                        \
      (const __attribute__((address_space(1))) void*)(srcp),               \
      (__attribute__((address_space(3))) void*)(dstp), 16, 0, 0)

// Stage pair P (tiles 2P, 2P+1) into slot P&1.  8 loads/thread.
#define STAGE_PAIR(P)                                                      \
  do {                                                                     \
    const size_t _kE = (size_t)(2 * (P)) * 64;                             \
    const size_t _kO = (size_t)(2 * (P) + 1) * 64;                         \
    uint8_t* _sb = ldsu + (((P) & 1) * 65536);                             \
    GL(aSrc + _kE, _sb + i * 16);                                          \
    GL(aSrc + _kE + (size_t)128 * K, _sb + i * 16 + 8192);                 \
    GL(aSrc + _kO, _sb + 16384 + i * 16);                                  \
    GL(aSrc + _kO + (size_t)128 * K, _sb + 16384 + i * 16 + 8192);         \
    GL(bSrc + _kE, _sb + 32768 + i * 16);                                  \
    GL(bSrc + _kE + (size_t)128 * K, _sb + 32768 + i * 16 + 8192);         \
    GL(bSrc + _kO, _sb + 49152 + i * 16);                                  \
    GL(bSrc + _kO + (size_t)128 * K, _sb + 49152 + i * 16 + 8192);         \
  } while (0)

  // ds_read_b128 offsets (within slot): row r, phys quad = kg ^ ((r>>1)&3).
  int offA[8], offB[4];
  const int qsw = (kg ^ ((wl >> 1) & 3)) * 16;
#pragma unroll
  for (int m = 0; m < 8; ++m) {
    const int r = wr * 128 + m * 16 + wl;
    offA[m] = r * 64 + qsw;            // A_E; A_O = +16384
  }
#pragma unroll
  for (int n = 0; n < 4; ++n) {
    const int r = wc * 64 + n * 16 + wl;
    offB[n] = 32768 + r * 64 + qsw;    // B_E; B_O = +16384
  }

  f32x4 acc[8][4] = {};
  i32x8 bF[4];

#define LOADA(dst, mm)                                                     \
  do {                                                                     \
    i32x4 _e = *reinterpret_cast<const i32x4*>(sb + offA[mm]);             \
    i32x4 _o = *reinterpret_cast<const i32x4*>(sb + offA[mm] + 16384);     \
    dst[0] = _e[0]; dst[1] = _e[1]; dst[2] = _e[2]; dst[3] = _e[3];        \
    dst[4] = _o[0]; dst[5] = _o[1]; dst[6] = _o[2]; dst[7] = _o[3];        \
  } while (0)

  // prologue: stage pair 0, drain fully, barrier
  STAGE_PAIR(0);
  asm volatile("s_waitcnt vmcnt(0)" ::: "memory");
  __builtin_amdgcn_s_barrier();
  __builtin_amdgcn_sched_barrier(0);

  for (int j = 0; j < nJ; ++j) {
    const uint8_t* sb = lds + (j & 1) * 65536;

    // B fragments (8 b128) -> bF[0..3]
#pragma unroll
    for (int n = 0; n < 4; ++n) {
      i32x4 be = *reinterpret_cast<const i32x4*>(sb + offB[n]);
      i32x4 bo = *reinterpret_cast<const i32x4*>(sb + offB[n] + 16384);
      bF[n][0] = be[0]; bF[n][1] = be[1]; bF[n][2] = be[2]; bF[n][3] = be[3];
      bF[n][4] = bo[0]; bF[n][5] = bo[1]; bF[n][6] = bo[2]; bF[n][7] = bo[3];
    }

    // stage pair j+1 into the OTHER slot (holds pair j-1: consumed and
    // barrier-retired before this iter began -> provably race-free)
    if (j + 1 < nJ) STAGE_PAIR(j + 1);

    // MFMA cluster with pipelined A-reads: read(m+1) before MFMA(m)
    __builtin_amdgcn_s_setprio(1);
    {
      i32x8 aCur, aNxt;
      LOADA(aCur, 0);
#pragma unroll
      for (int m = 0; m < 8; ++m) {
        if (m + 1 < 8) LOADA(aNxt, m + 1);
#pragma unroll
        for (int n = 0; n < 4; ++n)
          acc[m][n] = __builtin_amdgcn_mfma_scale_f32_16x16x128_f8f6f4(
              aCur, bF[n], acc[m][n], 0, 0, 0, SCALE_ONE, 0, SCALE_D64);
        aCur = aNxt;
      }
    }
    __builtin_amdgcn_s_setprio(0);

    // boundary: drain stage (issued ~2500 cyc ago -> ~free), barrier
    asm volatile("s_waitcnt vmcnt(0)" ::: "memory");
    __builtin_amdgcn_s_barrier();
    __builtin_amdgcn_sched_barrier(0);
  }

  // epilogue: C/D layout col=lane&15, row=(lane>>4)*4+reg (shape-determined)
#pragma unroll
  for (int mg = 0; mg < 8; ++mg)
#pragma unroll
    for (int ng = 0; ng < 4; ++ng)
#pragma unroll
      for (int r = 0; r < 4; ++r) {
        const int row = row0 + wr * 128 + mg * 16 + kg * 4 + r;
        const int col = col0 + wc * 64 + ng * 16 + wl;
        __hip_bfloat16 bv = __float2bfloat16(acc[mg][ng][r]);
        C[(size_t)row * V + col] = *reinterpret_cast<const uint16_t*>(&bv);
      }
#undef LOADA
#undef STAGE_PAIR
#undef GL
}

// ---------------------------------------------------------------- JSD rows
__device__ __forceinline__ void unpack8(uint4 v, float* f) {
  uint32_t w[4] = {v.x, v.y, v.z, v.w};
#pragma unroll
  for (int j = 0; j < 4; ++j) {
    union { uint32_t u; float x; } lo, hi;
    lo.u = (w[j] & 0xffffu) << 16;
    hi.u = w[j] & 0xffff0000u;
    f[2 * j] = lo.x;
    f[2 * j + 1] = hi.x;
  }
}

__device__ __forceinline__ float blockReduce(float v, float* sh) {
#pragma unroll
  for (int o = 32; o >= 1; o >>= 1) v += __shfl_xor(v, o, 64);
  const int w = threadIdx.x >> 6;
  __syncthreads();
  if ((threadIdx.x & 63) == 0) sh[w] = v;
  __syncthreads();
  float r = sh[0];
#pragma unroll
  for (int i = 1; i < 4; ++i) r += sh[i];
  return r;
}

// online-LSE load pass (1 global sweep, fused max+sum) + 1 LDS JSD pass.
__global__ __launch_bounds__(256) void jsd_rows_kernel(
    const uint16_t* __restrict__ SL, const uint16_t* __restrict__ TL,
    float* __restrict__ per_tok, int V) {
  __shared__ __align__(16) uint16_t rowS[32000];
  __shared__ __align__(16) uint16_t rowT[32000];
  __shared__ float redM[2][4], redS[2][4], red[4];

  const int t = threadIdx.x;
  const int row = blockIdx.x;
  const uint4* gS = reinterpret_cast<const uint4*>(SL + (size_t)row * V);
  const uint4* gT = reinterpret_cast<const uint4*>(TL + (size_t)row * V);
  uint4* lS = reinterpret_cast<uint4*>(rowS);
  uint4* lT = reinterpret_cast<uint4*>(rowT);
  const int nvec = V >> 3;  // 4000

  float mS = -3.0e38f, sS = 0.f, mT = -3.0e38f, sT = 0.f;
  for (int i = t; i < nvec; i += 256) {
    uint4 vs = gS[i], vt = gT[i];
    lS[i] = vs; lT[i] = vt;
    float fs[8], ft[8];
    unpack8(vs, fs);
    unpack8(vt, ft);
    float vmS = fs[0], vmT = ft[0];
#pragma unroll
    for (int j = 1; j < 8; ++j) { vmS = fmaxf(vmS, fs[j]); vmT = fmaxf(vmT, ft[j]); }
    if (vmS > mS) { sS *= __expf(mS - vmS); mS = vmS; }
    if (vmT > mT) { sT *= __expf(mT - vmT); mT = vmT; }
#pragma unroll
    for (int j = 0; j < 8; ++j) { sS += __expf(fs[j] - mS); sT += __expf(ft[j] - mT); }
  }

#pragma unroll
  for (int o = 32; o >= 1; o >>= 1) {
    float mo = __shfl_xor(mS, o, 64), so = __shfl_xor(sS, o, 64);
    float mn = fmaxf(mS, mo);
    sS = sS * __expf(mS - mn) + so * __expf(mo - mn); mS = mn;
    mo = __shfl_xor(mT, o, 64); so = __shfl_xor(sT, o, 64);
    mn = fmaxf(mT, mo);
    sT = sT * __expf(mT - mn) + so * __expf(mo - mn); mT = mn;
  }
  const int wv = t >> 6;
  if ((t & 63) == 0) {
    redM[0][wv] = mS; redS[0][wv] = sS;
    redM[1][wv] = mT; redS[1][wv] = sT;
  }
  __syncthreads();   // covers (m,s) publication AND the LDS row writes
  float M0 = redM[0][0], S0 = redS[0][0];
  float M1 = redM[1][0], S1 = redS[1][0];
#pragma unroll
  for (int k = 1; k < 4; ++k) {
    float m2 = redM[0][k], s2 = redS[0][k];
    float mn = fmaxf(M0, m2);
    S0 = S0 * __expf(M0 - mn) + s2 * __expf(m2 - mn); M0 = mn;
    m2 = redM[1][k]; s2 = redS[1][k];
    mn = fmaxf(M1, m2);
    S1 = S1 * __expf(M1 - mn) + s2 * __expf(m2 - mn); M1 = mn;
  }
  const float lseS = M0 + __logf(S0);
  const float lseT = M1 + __logf(S1);

  float acc = 0.f;
  for (int i = t; i < nvec; i += 256) {
    float fs[8], ft[8];
    unpack8(lS[i], fs);
    unpack8(lT[i], ft);
#pragma unroll
    for (int j = 0; j < 8; ++j) {
      const float lq = fs[j] - lseS;
      const float lp = ft[j] - lseT;
      const float q = __expf(lq);
      const float p = __expf(lp);
      const float m = BETA * p + (1.f - BETA) * q;
      const float lm = __logf(m);
      acc += BETA * p * (lp - lm) + (1.f - BETA) * q * (lq - lm);
    }
  }
  acc = blockReduce(acc, red);
  if (t == 0) per_tok[row] = acc;
}

// ---------------------------------------------------------------- finalize
__global__ __launch_bounds__(256) void finalize_kernel(
    const float* __restrict__ per_tok, const int* __restrict__ tgt,
    float* __restrict__ out, int N) {
  __shared__ float redf[4];
  __shared__ int redi[4];
  float s = 0.f;
  int c = 0;
  for (int i = threadIdx.x; i < N; i += 256) {
    if (tgt[i] != IGNORE_INDEX) { s += per_tok[i]; c += 1; }
  }
#pragma unroll
  for (int o = 32; o >= 1; o >>= 1) {
    s += __shfl_xor(s, o, 64);
    c += __shfl_xor(c, o, 64);
  }
  const int w = threadIdx.x >> 6;
  if ((threadIdx.x & 63) == 0) { redf[w] = s; redi[w] = c; }
  __syncthreads();
  if (threadIdx.x == 0) {
    float st = 0.f;
    int ct = 0;
#pragma unroll
    for (int i = 0; i < 4; ++i) { st += redf[i]; ct += redi[i]; }
    out[0] = st / (float)(ct > 0 ? ct : 1);
  }
}

// ---------------------------------------------------------------- launch
extern "C" void kernel_launch(void* const* d_in, const int* in_sizes, int n_in,
                              void* d_out, int out_size, void* d_ws, size_t ws_size,
                              hipStream_t stream) {
  const float* student = (const float*)d_in[0];
  const float* W_s     = (const float*)d_in[1];
  const float* teacher = (const float*)d_in[2];
  const float* W_t     = (const float*)d_in[3];
  const int*   target  = (const int*)d_in[4];

  const int N  = in_sizes[4];            // 2048
  const int Hs = in_sizes[0] / N;        // 2048
  const int Ht = in_sizes[2] / N;        // 4096
  const int V  = in_sizes[1] / Hs;       // 32000

  char* ws = (char*)d_ws;
  size_t off = 0;
  auto alloc = [&](size_t bytes) -> void* {
    void* p = ws + off;
    off += (bytes + 255) & ~(size_t)255;
    return p;
  };
  uint8_t* Sf8  = (uint8_t*)alloc((size_t)N * Hs);
  uint8_t* Wsf8 = (uint8_t*)alloc((size_t)V * Hs);
  uint8_t* Tf8  = (uint8_t*)alloc((size_t)N * Ht);
  uint8_t* Wtf8 = (uint8_t*)alloc((size_t)V * Ht);
  uint16_t* slog = (uint16_t*)alloc((size_t)N * V * 2);
  uint16_t* tlog = (uint16_t*)alloc((size_t)N * V * 2);
  float* per_tok = (float*)alloc((size_t)N * sizeof(float));
  (void)ws_size;  // total ~465 MB

  // fused convert: grid-stride, 8192-float chunks (boundaries all even
  // multiples of 4096 floats -> no chunk straddles an array)
  const int c0 = (N * Hs) / 8192;               // 512
  const int c1 = c0 + (V * Hs) / 8192;          // +8000
  const int c2 = c1 + (N * Ht) / 8192;          // +1024
  const int cT = c2 + (V * Ht) / 8192;          // +16000 = 25536
  fused_cvt_kernel<<<4096, 256, 0, stream>>>(
      student, Sf8, c0, W_s, Wsf8, c1, teacher, Tf8, c2, W_t, Wtf8, cT);

  const int RT = N / 256;   // 8
  const int CT = V / 256;   // 125
  // merged launch: teacher blocks first, student backfills the tail
  gemm_mx4_kernel<<<2 * RT * CT, 512, 0, stream>>>(
      Tf8, Wtf8, tlog, Ht, Sf8, Wsf8, slog, Hs, V, RT, CT);

  jsd_rows_kernel<<<N, 256, 0, stream>>>(slog, tlog, per_tok, V);
  finalize_kernel<<<1, 256, 0, stream>>>(per_tok, target, (float*)d_out, N);
}